// Round 1
// baseline (85.397 us; speedup 1.0000x reference)
//
#include <hip/hip_runtime.h>

// LGNLayer: retina matvec -> threshold fire -> LGN matvec+relu -> WTA row update.
// All f32. Outputs concatenated: new_firing[8192], lgn_act[2048],
// lgn_weights_new[2048*8192], lgn_threshold_new[2048].

constexpr int N_RET = 8192;
constexpr int N_LGN = 2048;
constexpr float ETA = 0.1f;
constexpr float MU_WTS = 2.5f;

// ---------- K1: new_firing = (retina_weights @ is_firing > retina_threshold) ----------
__global__ __launch_bounds__(256) void k_retina(
    const float* __restrict__ rw, const float* __restrict__ rthr,
    const float* __restrict__ firing, float* __restrict__ new_firing)
{
    const int row = blockIdx.x;
    const int t = threadIdx.x;
    const float4* __restrict__ wr = reinterpret_cast<const float4*>(rw + (size_t)row * N_RET);
    const float4* __restrict__ fr = reinterpret_cast<const float4*>(firing);
    float4 acc = make_float4(0.f, 0.f, 0.f, 0.f);
#pragma unroll
    for (int k = 0; k < (N_RET / 4) / 256; ++k) {   // 8 iterations
        const int j = t + k * 256;
        const float4 w = wr[j];
        const float4 f = fr[j];
        acc.x += w.x * f.x; acc.y += w.y * f.y;
        acc.z += w.z * f.z; acc.w += w.w * f.w;
    }
    float v = (acc.x + acc.y) + (acc.z + acc.w);
#pragma unroll
    for (int off = 32; off > 0; off >>= 1) v += __shfl_down(v, off, 64);
    __shared__ float s[4];
    const int lane = t & 63, wv = t >> 6;
    if (lane == 0) s[wv] = v;
    __syncthreads();
    if (t == 0) {
        const float x = (s[0] + s[1]) + (s[2] + s[3]);
        new_firing[row] = (x > rthr[row]) ? 1.0f : 0.0f;
    }
}

// ---------- K2: lgn_act = relu(lgn_weights @ new_firing); also copy weights row to out ----------
__global__ __launch_bounds__(256) void k_lgn(
    const float* __restrict__ lw, const float* __restrict__ firing,
    float* __restrict__ lgn_act, float* __restrict__ w_out)
{
    const int row = blockIdx.x;
    const int t = threadIdx.x;
    const float4* __restrict__ wr = reinterpret_cast<const float4*>(lw + (size_t)row * N_RET);
    const float4* __restrict__ fr = reinterpret_cast<const float4*>(firing);
    float4* __restrict__ wo = reinterpret_cast<float4*>(w_out + (size_t)row * N_RET);
    float4 acc = make_float4(0.f, 0.f, 0.f, 0.f);
#pragma unroll
    for (int k = 0; k < (N_RET / 4) / 256; ++k) {   // 8 iterations
        const int j = t + k * 256;
        const float4 w = wr[j];
        const float4 f = fr[j];
        wo[j] = w;                                  // fused copy of lgn_weights -> out
        acc.x += w.x * f.x; acc.y += w.y * f.y;
        acc.z += w.z * f.z; acc.w += w.w * f.w;
    }
    float v = (acc.x + acc.y) + (acc.z + acc.w);
#pragma unroll
    for (int off = 32; off > 0; off >>= 1) v += __shfl_down(v, off, 64);
    __shared__ float s[4];
    const int lane = t & 63, wv = t >> 6;
    if (lane == 0) s[wv] = v;
    __syncthreads();
    if (t == 0) {
        const float x = (s[0] + s[1]) + (s[2] + s[3]);
        lgn_act[row] = fmaxf(x, 0.0f);
    }
}

// ---------- K3: argmax(act) with first-index ties; write (val, idx) to ws; threshold output ----------
__global__ __launch_bounds__(256) void k_argmax(
    const float* __restrict__ lgn_act, const float* __restrict__ lthr,
    float* __restrict__ thr_out, float* __restrict__ ws)
{
    const int t = threadIdx.x;
    float bv = -1.0f;           // act >= 0 always, so any real value wins
    int bi = 0x40000000;
    for (int k = 0; k < N_LGN / 256; ++k) {   // 8 iterations, ascending j per thread
        const int j = t + k * 256;
        const float a = fmaxf(lgn_act[j] - lthr[j], 0.0f);
        if (a > bv) { bv = a; bi = j; }       // strict > keeps earliest index
    }
#pragma unroll
    for (int off = 32; off > 0; off >>= 1) {
        const float ov = __shfl_down(bv, off, 64);
        const int oi = __shfl_down(bi, off, 64);
        if (ov > bv || (ov == bv && oi < bi)) { bv = ov; bi = oi; }
    }
    __shared__ float sv[4];
    __shared__ int si[4];
    __shared__ float fval;
    __shared__ int fidx;
    const int lane = t & 63, wv = t >> 6;
    if (lane == 0) { sv[wv] = bv; si[wv] = bi; }
    __syncthreads();
    if (t == 0) {
        float v = sv[0]; int i = si[0];
#pragma unroll
        for (int k = 1; k < 4; ++k)
            if (sv[k] > v || (sv[k] == v && si[k] < i)) { v = sv[k]; i = si[k]; }
        fval = v; fidx = i;
        ws[0] = v;
        reinterpret_cast<int*>(ws)[1] = i;
    }
    __syncthreads();
    const float val = fval;
    const int idx = fidx;
    for (int k = 0; k < N_LGN / 256; ++k) {
        const int j = t + k * 256;
        float tv = lthr[j];
        if (val > 0.0f && j == idx) tv += 0.005f * val;
        thr_out[j] = tv;
    }
}

// ---------- K4: winner row update: row = ((w + a) + a) / mean * MU_WTS ----------
__global__ __launch_bounds__(256) void k_rowupd(
    const float* __restrict__ lw, const float* __restrict__ firing,
    const float* __restrict__ ws, float* __restrict__ w_out)
{
    const float val = ws[0];
    if (!(val > 0.0f)) return;   // uniform across block: no update
    const int idx = reinterpret_cast<const int*>(ws)[1];
    const int t = threadIdx.x;
    const float* __restrict__ wr = lw + (size_t)idx * N_RET;
    float* __restrict__ wo = w_out + (size_t)idx * N_RET;
    __shared__ float buf[N_RET];   // 32 KB
    const float av = 0.5f * (ETA * val);
    float part = 0.0f;
    for (int k = 0; k < N_RET / 256; ++k) {   // 32 iterations
        const int j = t + k * 256;
        const float a = (firing[j] != 0.0f) ? av : 0.0f;
        const float x = (wr[j] + a) + a;      // two half-additions, like reference
        buf[j] = x;
        part += x;
    }
#pragma unroll
    for (int off = 32; off > 0; off >>= 1) part += __shfl_down(part, off, 64);
    __shared__ float s[4];
    __shared__ float mean_s;
    const int lane = t & 63, wv = t >> 6;
    if (lane == 0) s[wv] = part;
    __syncthreads();
    if (t == 0) {
        const float sum = (s[0] + s[1]) + (s[2] + s[3]);
        mean_s = sum / (float)N_RET;
    }
    __syncthreads();
    const float m = mean_s;
    for (int k = 0; k < N_RET / 256; ++k) {
        const int j = t + k * 256;
        wo[j] = buf[j] / m * MU_WTS;
    }
}

extern "C" void kernel_launch(void* const* d_in, const int* in_sizes, int n_in,
                              void* d_out, int out_size, void* d_ws, size_t ws_size,
                              hipStream_t stream)
{
    const float* rw   = (const float*)d_in[0];   // retina_weights [8192, 8192]
    const float* rthr = (const float*)d_in[1];   // retina_threshold [8192]
    const float* lw   = (const float*)d_in[2];   // lgn_weights [2048, 8192]
    const float* lthr = (const float*)d_in[3];   // lgn_threshold [2048]
    const float* fir  = (const float*)d_in[4];   // is_firing [8192]

    float* out   = (float*)d_out;
    float* o_fir = out;                                        // [8192]
    float* o_act = out + N_RET;                                // [2048]
    float* o_w   = out + N_RET + N_LGN;                        // [2048*8192]
    float* o_thr = out + N_RET + N_LGN + (size_t)N_LGN * N_RET; // [2048]
    float* ws    = (float*)d_ws;                               // [val f32][idx i32]

    hipLaunchKernelGGL(k_retina, dim3(N_RET), dim3(256), 0, stream, rw, rthr, fir, o_fir);
    hipLaunchKernelGGL(k_lgn,    dim3(N_LGN), dim3(256), 0, stream, lw, o_fir, o_act, o_w);
    hipLaunchKernelGGL(k_argmax, dim3(1),     dim3(256), 0, stream, o_act, lthr, o_thr, ws);
    hipLaunchKernelGGL(k_rowupd, dim3(1),     dim3(256), 0, stream, lw, o_fir, ws, o_w);
}

// Round 3
// 75.829 us; speedup vs baseline: 1.1262x; 1.1262x over previous
//
#include <hip/hip_runtime.h>

// LGNLayer: retina matvec -> threshold fire -> LGN matvec+relu -> WTA row update.
// All f32. Outputs concatenated: new_firing[8192], lgn_act[2048],
// lgn_weights_new[2048*8192], lgn_threshold_new[2048].
//
// 3 kernels: k_retina (256MB stream), k_lgn (64MB read + 64MB copy-out, fused),
// k_wta (argmax + threshold + winner-row update, single block).

constexpr int N_RET = 8192;
constexpr int N_LGN = 2048;
constexpr float ETA = 0.1f;
constexpr float MU_WTS = 2.5f;

// native clang vector type: __builtin_nontemporal_* requires scalar/vector,
// not HIP_vector_type structs
typedef float vf4 __attribute__((ext_vector_type(4)));

__device__ __forceinline__ vf4 ntload4(const float* p) {
    return __builtin_nontemporal_load(reinterpret_cast<const vf4*>(p));
}
__device__ __forceinline__ void ntstore4(float* p, vf4 v) {
    __builtin_nontemporal_store(v, reinterpret_cast<vf4*>(p));
}
__device__ __forceinline__ vf4 ld4(const float* p) {
    return *reinterpret_cast<const vf4*>(p);
}
__device__ __forceinline__ void st4(float* p, vf4 v) {
    *reinterpret_cast<vf4*>(p) = v;
}

// ---------- K1: new_firing = (retina_weights @ is_firing > retina_threshold) ----------
__global__ __launch_bounds__(256) void k_retina(
    const float* __restrict__ rw, const float* __restrict__ rthr,
    const float* __restrict__ firing, float* __restrict__ new_firing)
{
    const int row = blockIdx.x;
    const int t = threadIdx.x;
    const float* __restrict__ wr = rw + (size_t)row * N_RET;
    vf4 acc = (vf4)(0.0f);
#pragma unroll
    for (int k = 0; k < (N_RET / 4) / 256; ++k) {   // 8 iterations
        const int j = (t + k * 256) * 4;
        const vf4 w = ntload4(wr + j);              // streaming, no reuse
        const vf4 f = ld4(firing + j);              // cached, reused by all blocks
        acc += w * f;
    }
    float v = (acc.x + acc.y) + (acc.z + acc.w);
#pragma unroll
    for (int off = 32; off > 0; off >>= 1) v += __shfl_down(v, off, 64);
    __shared__ float s[4];
    const int lane = t & 63, wv = t >> 6;
    if (lane == 0) s[wv] = v;
    __syncthreads();
    if (t == 0) {
        const float x = (s[0] + s[1]) + (s[2] + s[3]);
        new_firing[row] = (x > rthr[row]) ? 1.0f : 0.0f;
    }
}

// ---------- K2: lgn_act = relu(lgn_weights @ new_firing); fused copy weights -> out ----------
__global__ __launch_bounds__(256) void k_lgn(
    const float* __restrict__ lw, const float* __restrict__ firing,
    float* __restrict__ lgn_act, float* __restrict__ w_out)
{
    const int row = blockIdx.x;
    const int t = threadIdx.x;
    const float* __restrict__ wr = lw + (size_t)row * N_RET;
    float* __restrict__ wo = w_out + (size_t)row * N_RET;
    vf4 acc = (vf4)(0.0f);
#pragma unroll
    for (int k = 0; k < (N_RET / 4) / 256; ++k) {   // 8 iterations
        const int j = (t + k * 256) * 4;
        const vf4 w = ntload4(wr + j);              // streaming
        const vf4 f = ld4(firing + j);
        ntstore4(wo + j, w);                        // fused copy, streaming store
        acc += w * f;
    }
    float v = (acc.x + acc.y) + (acc.z + acc.w);
#pragma unroll
    for (int off = 32; off > 0; off >>= 1) v += __shfl_down(v, off, 64);
    __shared__ float s[4];
    const int lane = t & 63, wv = t >> 6;
    if (lane == 0) s[wv] = v;
    __syncthreads();
    if (t == 0) {
        const float x = (s[0] + s[1]) + (s[2] + s[3]);
        lgn_act[row] = fmaxf(x, 0.0f);
    }
}

// ---------- K3: argmax + threshold output + winner-row update (single block, 1024 thr) ----------
__global__ __launch_bounds__(1024) void k_wta(
    const float* __restrict__ lgn_act, const float* __restrict__ lthr,
    const float* __restrict__ lw, const float* __restrict__ firing,
    float* __restrict__ thr_out, float* __restrict__ w_out)
{
    const int t = threadIdx.x;
    const int lane = t & 63, wv = t >> 6;
    __shared__ float sv[16];
    __shared__ int si[16];
    __shared__ float s_val;
    __shared__ int s_idx;

    // --- argmax(act) with first-index tie-break ---
    float bv = -1.0f;           // act >= 0 always
    int bi = 0x40000000;
#pragma unroll
    for (int k = 0; k < N_LGN / 1024; ++k) {   // 2 iterations, ascending j
        const int j = t + k * 1024;
        const float a = fmaxf(lgn_act[j] - lthr[j], 0.0f);
        if (a > bv) { bv = a; bi = j; }        // strict > keeps earliest index
    }
#pragma unroll
    for (int off = 32; off > 0; off >>= 1) {
        const float ov = __shfl_down(bv, off, 64);
        const int oi = __shfl_down(bi, off, 64);
        if (ov > bv || (ov == bv && oi < bi)) { bv = ov; bi = oi; }
    }
    if (lane == 0) { sv[wv] = bv; si[wv] = bi; }
    __syncthreads();
    if (t == 0) {
        float v = sv[0]; int i = si[0];
#pragma unroll
        for (int k = 1; k < 16; ++k)
            if (sv[k] > v || (sv[k] == v && si[k] < i)) { v = sv[k]; i = si[k]; }
        s_val = v; s_idx = i;
    }
    __syncthreads();
    const float val = s_val;
    const int idx = s_idx;

    // --- threshold output ---
#pragma unroll
    for (int k = 0; k < N_LGN / 1024; ++k) {
        const int j = t + k * 1024;
        float tv = lthr[j];
        if (val > 0.0f && j == idx) tv += 0.005f * val;
        thr_out[j] = tv;
    }
    if (!(val > 0.0f)) return;   // uniform: no weight update

    // --- winner row: x = (w + a) + a; row = x / mean(x) * MU_WTS ---
    const float* __restrict__ wr = lw + (size_t)idx * N_RET;
    float* __restrict__ wo = w_out + (size_t)idx * N_RET;
    const float av = 0.5f * (ETA * val);   // exact: a = av * f for f in {0,1}

    vf4 x[2];
    float part = 0.0f;
#pragma unroll
    for (int k = 0; k < (N_RET / 4) / 1024; ++k) {   // 2 iterations
        const int j = (t + k * 1024) * 4;
        const vf4 w = ld4(wr + j);
        const vf4 f = ld4(firing + j);
        vf4 v = (w + av * f) + av * f;               // two half-additions, like ref
        x[k] = v;
        part += (v.x + v.y) + (v.z + v.w);
    }
#pragma unroll
    for (int off = 32; off > 0; off >>= 1) part += __shfl_down(part, off, 64);
    __shared__ float red[16];
    __shared__ float s_mean;
    if (lane == 0) red[wv] = part;
    __syncthreads();
    if (t == 0) {
        float sum = 0.0f;
#pragma unroll
        for (int k = 0; k < 16; ++k) sum += red[k];
        s_mean = sum / (float)N_RET;
    }
    __syncthreads();
    const float m = s_mean;
#pragma unroll
    for (int k = 0; k < (N_RET / 4) / 1024; ++k) {
        const int j = (t + k * 1024) * 4;
        st4(wo + j, x[k] / m * MU_WTS);
    }
}

extern "C" void kernel_launch(void* const* d_in, const int* in_sizes, int n_in,
                              void* d_out, int out_size, void* d_ws, size_t ws_size,
                              hipStream_t stream)
{
    const float* rw   = (const float*)d_in[0];   // retina_weights [8192, 8192]
    const float* rthr = (const float*)d_in[1];   // retina_threshold [8192]
    const float* lw   = (const float*)d_in[2];   // lgn_weights [2048, 8192]
    const float* lthr = (const float*)d_in[3];   // lgn_threshold [2048]
    const float* fir  = (const float*)d_in[4];   // is_firing [8192]

    float* out   = (float*)d_out;
    float* o_fir = out;                                         // [8192]
    float* o_act = out + N_RET;                                 // [2048]
    float* o_w   = out + N_RET + N_LGN;                         // [2048*8192]
    float* o_thr = out + N_RET + N_LGN + (size_t)N_LGN * N_RET; // [2048]

    hipLaunchKernelGGL(k_retina, dim3(N_RET), dim3(256),  0, stream, rw, rthr, fir, o_fir);
    hipLaunchKernelGGL(k_lgn,    dim3(N_LGN), dim3(256),  0, stream, lw, o_fir, o_act, o_w);
    hipLaunchKernelGGL(k_wta,    dim3(1),     dim3(1024), 0, stream, o_act, lthr, lw, o_fir, o_thr, o_w);
}